// Round 1
// baseline (665.870 us; speedup 1.0000x reference)
//
#include <hip/hip_runtime.h>

#define BEV_H 512
#define BEV_W 512
#define BEV_HW (BEV_H * BEV_W)
#define NB 8
#define NP 30000
#define NC 64

// Phase 2: record, per BEV cell, the highest pillar index p that maps to it.
// Matches numpy/JAX-CPU scatter "last write wins" semantics (highest p wins).
__global__ void scatter_winner_kernel(const int* __restrict__ coords,
                                      int* __restrict__ winner) {
    int idx = blockIdx.x * blockDim.x + threadIdx.x;   // over NB*NP
    if (idx >= NB * NP) return;
    int b = idx / NP;
    int p = idx - b * NP;
    int2 c2 = ((const int2*)coords)[idx];              // coords[b][p][{x,y}]
    int gx = c2.x;
    int gy = c2.y;
    if (gx >= 0 && gx < BEV_W && gy >= 0 && gy < BEV_H) {
        atomicMax(&winner[b * BEV_HW + gy * BEV_W + gx], p);
    }
}

// Phase 3 (restructured): one thread owns 4 consecutive cells of one batch
// and emits ALL 64 channels for them.
//  - winner read ONCE per cell (was 64x: 512 MB -> 8 MB of winner traffic)
//  - feature rows read as float4 chunks by the same thread (was 14.5M random
//    scalar 4-B gathers; now 3.6M 16-B gathers, consecutive chunks hit the
//    same 64-B line -> every fetched line fully consumed, feat read = 61 MB)
//  - output stores stay float4-coalesced via a 4x4 register transpose.
// Invalid cells clamp their row pointer to row 0 (same-address broadcast,
// L1-hit) and are cndmask'd to zero -- no divergent load path.
__global__ void __launch_bounds__(256)
gather_out_kernel(const float* __restrict__ feat,
                  const int* __restrict__ winner,
                  float* __restrict__ out) {
    const int b    = blockIdx.y;
    const int cell = (blockIdx.x * blockDim.x + threadIdx.x) << 2;  // 4 cells

    const int4 w4 = *(const int4*)(winner + (size_t)b * BEV_HW + cell);

    const float* __restrict__ fb = feat + (size_t)b * NP * NC;
    const float* __restrict__ r0 = fb + (size_t)(w4.x < 0 ? 0 : w4.x) * NC;
    const float* __restrict__ r1 = fb + (size_t)(w4.y < 0 ? 0 : w4.y) * NC;
    const float* __restrict__ r2 = fb + (size_t)(w4.z < 0 ? 0 : w4.z) * NC;
    const float* __restrict__ r3 = fb + (size_t)(w4.w < 0 ? 0 : w4.w) * NC;

    float* __restrict__ ob = out + (size_t)b * NC * BEV_HW + cell;

    #pragma unroll 2
    for (int c0 = 0; c0 < NC; c0 += 4) {
        // 4 independent 16-B gathers (cells 0..3, channels c0..c0+3)
        float4 va = *(const float4*)(r0 + c0);
        float4 vb = *(const float4*)(r1 + c0);
        float4 vc = *(const float4*)(r2 + c0);
        float4 vd = *(const float4*)(r3 + c0);
        if (w4.x < 0) va = make_float4(0.f, 0.f, 0.f, 0.f);
        if (w4.y < 0) vb = make_float4(0.f, 0.f, 0.f, 0.f);
        if (w4.z < 0) vc = make_float4(0.f, 0.f, 0.f, 0.f);
        if (w4.w < 0) vd = make_float4(0.f, 0.f, 0.f, 0.f);

        // 4x4 register transpose -> coalesced float4 stores, one per channel
        *(float4*)(ob + (size_t)(c0 + 0) * BEV_HW) = make_float4(va.x, vb.x, vc.x, vd.x);
        *(float4*)(ob + (size_t)(c0 + 1) * BEV_HW) = make_float4(va.y, vb.y, vc.y, vd.y);
        *(float4*)(ob + (size_t)(c0 + 2) * BEV_HW) = make_float4(va.z, vb.z, vc.z, vd.z);
        *(float4*)(ob + (size_t)(c0 + 3) * BEV_HW) = make_float4(va.w, vb.w, vc.w, vd.w);
    }
}

extern "C" void kernel_launch(void* const* d_in, const int* in_sizes, int n_in,
                              void* d_out, int out_size, void* d_ws, size_t ws_size,
                              hipStream_t stream) {
    const float* feat   = (const float*)d_in[0];   // (8, 30000, 64) f32
    const int*   coords = (const int*)d_in[1];     // (8, 30000, 2) i32
    float*       out    = (float*)d_out;           // (8, 64, 512, 512) f32
    int*         winner = (int*)d_ws;              // NB*BEV_HW ints = 8 MB

    // Phase 1: winner = -1 everywhere (0xFF bytes). Capturable memset node.
    hipMemsetAsync(winner, 0xFF, (size_t)NB * BEV_HW * sizeof(int), stream);

    // Phase 2: atomicMax scatter of pillar indices.
    {
        int total = NB * NP;
        int block = 256;
        int grid  = (total + block - 1) / block;
        scatter_winner_kernel<<<grid, block, 0, stream>>>(coords, winner);
    }

    // Phase 3: gather + coalesced write of the full (8,64,512,512) output,
    // all channels per thread.
    {
        dim3 block(256, 1, 1);
        dim3 grid(BEV_HW / (4 * 256), NB, 1);      // 256 x 8 = 2048 blocks
        gather_out_kernel<<<grid, block, 0, stream>>>(feat, winner, out);
    }
}

// Round 2
// 587.099 us; speedup vs baseline: 1.1342x; 1.1342x over previous
//
#include <hip/hip_runtime.h>

#define BEV_H 512
#define BEV_W 512
#define BEV_HW (BEV_H * BEV_W)
#define NB 8
#define NP 30000
#define NC 64

// Phase 2: record, per BEV cell, the highest pillar index p that maps to it.
// Matches numpy/JAX-CPU scatter "last write wins" semantics (highest p wins).
__global__ void scatter_winner_kernel(const int* __restrict__ coords,
                                      int* __restrict__ winner) {
    int idx = blockIdx.x * blockDim.x + threadIdx.x;   // over NB*NP
    if (idx >= NB * NP) return;
    int b = idx / NP;
    int p = idx - b * NP;
    int2 c2 = ((const int2*)coords)[idx];              // coords[b][p][{x,y}]
    int gx = c2.x;
    int gy = c2.y;
    if (gx >= 0 && gx < BEV_W && gy >= 0 && gy < BEV_H) {
        atomicMax(&winner[b * BEV_HW + gy * BEV_W + gx], p);
    }
}

// Phase 3: one thread = 4 consecutive cells x 16 channels (one channel-group).
// Balance point between round-0 (1 channel/thread: max TLP, but feat-line
// reuse left to L2) and round-1 (64 channels/thread: perfect reuse, but TLP
// collapsed and each thread was a chain of 16 gather->wait->store trips).
//  - each valid feat row visit fetches exactly one 64-B line (16 channels x
//    4 B), fully consumed by this thread -> feat HBM fetch ~59 MB by
//    construction, no reliance on cache capture
//  - exactly ONE memory round trip per thread: 16 independent float4
//    gathers, one waitcnt, 4x4x4 register transpose, 16 coalesced stores
//  - 2M threads = 32K waves -> latency hidden by TLP again
// Invalid cells clamp to row 0 (lanes merge to one transaction) and are
// selected to zero after the load.
__global__ void __launch_bounds__(256)
gather_out_kernel(const float* __restrict__ feat,
                  const int* __restrict__ winner,
                  float* __restrict__ out) {
    const int b    = blockIdx.y >> 2;                 // batch
    const int g    = blockIdx.y & 3;                  // channel group: 16 ch
    const int cell = (blockIdx.x * blockDim.x + threadIdx.x) << 2;  // 4 cells

    const int4 w4 = *(const int4*)(winner + (size_t)b * BEV_HW + cell);
    const int w[4] = {w4.x, w4.y, w4.z, w4.w};

    const float* __restrict__ fb = feat + (size_t)b * NP * NC + g * 16;

    // 16 independent 16-B gathers: v[k][j] = cells k, channels g*16+4j..+3
    float4 v[4][4];
    #pragma unroll
    for (int k = 0; k < 4; ++k) {
        const float* __restrict__ rk = fb + (size_t)(w[k] < 0 ? 0 : w[k]) * NC;
        #pragma unroll
        for (int j = 0; j < 4; ++j)
            v[k][j] = *(const float4*)(rk + 4 * j);
    }

    #pragma unroll
    for (int k = 0; k < 4; ++k) {
        if (w[k] < 0) {
            #pragma unroll
            for (int j = 0; j < 4; ++j)
                v[k][j] = make_float4(0.f, 0.f, 0.f, 0.f);
        }
    }

    // Transpose -> one coalesced float4 store per channel plane (16 planes)
    float* __restrict__ ob =
        out + (size_t)b * NC * BEV_HW + (size_t)(g * 16) * BEV_HW + cell;
    #pragma unroll
    for (int j = 0; j < 4; ++j) {
        *(float4*)(ob + (size_t)(4 * j + 0) * BEV_HW) =
            make_float4(v[0][j].x, v[1][j].x, v[2][j].x, v[3][j].x);
        *(float4*)(ob + (size_t)(4 * j + 1) * BEV_HW) =
            make_float4(v[0][j].y, v[1][j].y, v[2][j].y, v[3][j].y);
        *(float4*)(ob + (size_t)(4 * j + 2) * BEV_HW) =
            make_float4(v[0][j].z, v[1][j].z, v[2][j].z, v[3][j].z);
        *(float4*)(ob + (size_t)(4 * j + 3) * BEV_HW) =
            make_float4(v[0][j].w, v[1][j].w, v[2][j].w, v[3][j].w);
    }
}

extern "C" void kernel_launch(void* const* d_in, const int* in_sizes, int n_in,
                              void* d_out, int out_size, void* d_ws, size_t ws_size,
                              hipStream_t stream) {
    const float* feat   = (const float*)d_in[0];   // (8, 30000, 64) f32
    const int*   coords = (const int*)d_in[1];     // (8, 30000, 2) i32
    float*       out    = (float*)d_out;           // (8, 64, 512, 512) f32
    int*         winner = (int*)d_ws;              // NB*BEV_HW ints = 8 MB

    // Phase 1: winner = -1 everywhere (0xFF bytes). Capturable memset node.
    hipMemsetAsync(winner, 0xFF, (size_t)NB * BEV_HW * sizeof(int), stream);

    // Phase 2: atomicMax scatter of pillar indices.
    {
        int total = NB * NP;
        int block = 256;
        int grid  = (total + block - 1) / block;
        scatter_winner_kernel<<<grid, block, 0, stream>>>(coords, winner);
    }

    // Phase 3: gather + coalesced write of the full (8,64,512,512) output.
    // 4 cells x 16 channels per thread.
    {
        dim3 block(256, 1, 1);
        dim3 grid(BEV_HW / (4 * 256), NB * 4, 1);  // 256 x 32 = 8192 blocks
        gather_out_kernel<<<grid, block, 0, stream>>>(feat, winner, out);
    }
}

// Round 4
// 571.568 us; speedup vs baseline: 1.1650x; 1.0272x over previous
//
#include <hip/hip_runtime.h>

#define BEV_H 512
#define BEV_W 512
#define BEV_HW (BEV_H * BEV_W)
#define NB 8
#define NP 30000
#define NC 64

typedef float floatx4 __attribute__((ext_vector_type(4)));

// Phase 2: record, per BEV cell, the highest pillar index p that maps to it.
// Matches numpy/JAX-CPU scatter "last write wins" semantics (highest p wins).
__global__ void scatter_winner_kernel(const int* __restrict__ coords,
                                      int* __restrict__ winner) {
    int idx = blockIdx.x * blockDim.x + threadIdx.x;   // over NB*NP
    if (idx >= NB * NP) return;
    int b = idx / NP;
    int p = idx - b * NP;
    int2 c2 = ((const int2*)coords)[idx];              // coords[b][p][{x,y}]
    int gx = c2.x;
    int gy = c2.y;
    if (gx >= 0 && gx < BEV_W && gy >= 0 && gy < BEV_H) {
        atomicMax(&winner[b * BEV_HW + gy * BEV_W + gx], p);
    }
}

// Phase 3, round-3 design: MINIMAL thread body, MAXIMAL TLP.
// One thread = 4 consecutive cells x 4 channels (one channel-quad g).
//   - int4 winner load, 4 independent float4 gathers, 4x4 transpose,
//     4 coalesced nontemporal float4 stores. ~40 VGPR -> 8 waves/SIMD,
//     131K waves (4x round-2) -> short single round trip per wave,
//     latency hidden by TLP like the 78%-of-peak fill kernel.
//   - feat 64-B line covers 16 ch = 4 g-quads; those 4 blocks are
//     dispatch-adjacent (delta=256 blocks, 256%8==0 -> SAME XCD) so the
//     line is fetched once and reused out of the same L2.
//   - winner re-read x16 = 128 MB, L2-resident (~4 us at L2 BW).
//   - output stores nontemporal (via native ext_vector_type; HIP float4
//     is a class and the builtin rejects it): 537 MB stream never
//     re-read; keep L2 for feat rows + winner.
__global__ void __launch_bounds__(256)
gather_out_kernel(const float* __restrict__ feat,
                  const int* __restrict__ winner,
                  float* __restrict__ out) {
    const int b    = blockIdx.y >> 4;                 // batch
    const int g    = blockIdx.y & 15;                 // channel quad: 4g..4g+3
    const int cell = (blockIdx.x * blockDim.x + threadIdx.x) << 2;  // 4 cells

    const int4 w4 = *(const int4*)(winner + (size_t)b * BEV_HW + cell);
    const int w[4] = {w4.x, w4.y, w4.z, w4.w};

    const float* __restrict__ fb = feat + (size_t)b * NP * NC + g * 4;

    // 4 independent 16-B gathers: v[k] = cell k, channels 4g..4g+3
    float4 v[4];
    #pragma unroll
    for (int k = 0; k < 4; ++k) {
        const float* __restrict__ rk = fb + (size_t)(w[k] < 0 ? 0 : w[k]) * NC;
        v[k] = *(const float4*)rk;
    }
    #pragma unroll
    for (int k = 0; k < 4; ++k) {
        if (w[k] < 0) v[k] = make_float4(0.f, 0.f, 0.f, 0.f);
    }

    // Transpose -> one coalesced float4 store per channel plane (4 planes)
    float* __restrict__ ob =
        out + ((size_t)b * NC + g * 4) * BEV_HW + cell;
    floatx4 s0 = {v[0].x, v[1].x, v[2].x, v[3].x};
    floatx4 s1 = {v[0].y, v[1].y, v[2].y, v[3].y};
    floatx4 s2 = {v[0].z, v[1].z, v[2].z, v[3].z};
    floatx4 s3 = {v[0].w, v[1].w, v[2].w, v[3].w};
    __builtin_nontemporal_store(s0, (floatx4*)(ob + (size_t)0 * BEV_HW));
    __builtin_nontemporal_store(s1, (floatx4*)(ob + (size_t)1 * BEV_HW));
    __builtin_nontemporal_store(s2, (floatx4*)(ob + (size_t)2 * BEV_HW));
    __builtin_nontemporal_store(s3, (floatx4*)(ob + (size_t)3 * BEV_HW));
}

extern "C" void kernel_launch(void* const* d_in, const int* in_sizes, int n_in,
                              void* d_out, int out_size, void* d_ws, size_t ws_size,
                              hipStream_t stream) {
    const float* feat   = (const float*)d_in[0];   // (8, 30000, 64) f32
    const int*   coords = (const int*)d_in[1];     // (8, 30000, 2) i32
    float*       out    = (float*)d_out;           // (8, 64, 512, 512) f32
    int*         winner = (int*)d_ws;              // NB*BEV_HW ints = 8 MB

    // Phase 1: winner = -1 everywhere (0xFF bytes). Capturable memset node.
    hipMemsetAsync(winner, 0xFF, (size_t)NB * BEV_HW * sizeof(int), stream);

    // Phase 2: atomicMax scatter of pillar indices.
    {
        int total = NB * NP;
        int block = 256;
        int grid  = (total + block - 1) / block;
        scatter_winner_kernel<<<grid, block, 0, stream>>>(coords, winner);
    }

    // Phase 3: gather + coalesced write of the full (8,64,512,512) output.
    // 4 cells x 4 channels per thread.
    {
        dim3 block(256, 1, 1);
        dim3 grid(BEV_HW / (4 * 256), NB * 16, 1);  // 256 x 128 = 32768 blocks
        gather_out_kernel<<<grid, block, 0, stream>>>(feat, winner, out);
    }
}